// Round 11
// baseline (247.913 us; speedup 1.0000x reference)
//
#include <hip/hip_runtime.h>
#include <hip/hip_bf16.h>

// MHA: B=4 T=2048 C=1024 H=16 D=64, fp32 in/out, bf16 MFMA internally.
// R19: REVERT to R16 (best measured: 236.6us, and that was on a ~4%-slow
//      clock). R17 (T14 array prefetch) hit rule-#20 scratch demotion
//      (249MB scratch writes); R18 (named-scalar retry) fixed scratch but
//      cost ~10-14us clock-normalized: the 3rd barrier/round + 32 VGPR
//      outweigh latency already hidden by TLP at 3 blocks/CU. T14 is
//      abandoned for this attn structure. This file is byte-identical to
//      R16: prep fusion + merged 128^2 QKV gemm_bt + balanced-perm attn
//      (per-f P, single fence, shared V reads, setprio) + proj64.

typedef unsigned short u16;
typedef __bf16 bf16_t;
typedef bf16_t bf16x8 __attribute__((ext_vector_type(8)));
typedef float f32x4 __attribute__((ext_vector_type(4)));
typedef u16 u16x8 __attribute__((ext_vector_type(8)));
typedef const __attribute__((address_space(1))) void* as1cv;
typedef __attribute__((address_space(3))) void* as3v;

#define BB 4
#define TT 2048
#define CC 1024
#define HH 16
#define DD 64

static __device__ __forceinline__ u16 f2bf(float f) {
  union { float f; unsigned int u; } x; x.f = f;
  unsigned int u = x.u;
  u += 0x7fff + ((u >> 16) & 1);   // round-to-nearest-even
  return (u16)(u >> 16);
}

// pack two f32 -> two bf16 (truncation) in one v_perm_b32
static __device__ __forceinline__ unsigned int pack2(float lo, float hi) {
  return __builtin_amdgcn_perm(__float_as_uint(hi), __float_as_uint(lo),
                               0x07060302u);
}

// ---------------- fused prep: x cast + w_qkv^T + w_proj^T ------------------
// blocks [0,8192): cast x (fp32->bf16, 4/thread)
// blocks [8192,11264): transpose+cast w_qkv [1024][3072] -> [3072][1024]
// blocks [11264,12288): transpose+cast w_proj [1024][1024] -> [1024][1024]
__global__ __launch_bounds__(256) void prep(
    const float* __restrict__ x, u16* __restrict__ xb,
    const float* __restrict__ w_qkv, u16* __restrict__ wqkvT,
    const float* __restrict__ w_proj, u16* __restrict__ wprojT) {
  __shared__ float tile[32][33];
  const int id = blockIdx.x;
  if (id < 8192) {
    int i = (id * 256 + threadIdx.x) * 4;
    float4 v = *(const float4*)(x + i);
    ushort4 o;
    o.x = f2bf(v.x); o.y = f2bf(v.y); o.z = f2bf(v.z); o.w = f2bf(v.w);
    *(ushort4*)(xb + i) = o;
    return;
  }
  const float* in; u16* out; int N, n0, k0;
  if (id < 11264) {
    int i = id - 8192;
    in = w_qkv; out = wqkvT; N = 3072;
    n0 = (i % 96) * 32; k0 = (i / 96) * 32;
  } else {
    int i = id - 11264;
    in = w_proj; out = wprojT; N = 1024;
    n0 = (i & 31) * 32; k0 = (i >> 5) * 32;
  }
  const int tx = threadIdx.x & 31, ty = threadIdx.x >> 5;  // 32 x 8
#pragma unroll
  for (int i = 0; i < 32; i += 8)
    tile[ty + i][tx] = in[(size_t)(k0 + ty + i) * N + n0 + tx];
  __syncthreads();
#pragma unroll
  for (int i = 0; i < 32; i += 8)
    out[(size_t)(n0 + ty + i) * 1024 + k0 + tx] = f2bf(tile[tx][ty + i]);
}

// ---------------- GEMM: C[M][N] = A[M][K](bf16) * Bt[N][K]^T + bias --------
// BK=64: per round 8 global_load_lds + 2 sub-steps of (8 ds_read_b128 +
// 16 MFMA). LDS phys 16B slot = logical blk ^ (row & 7).
__global__ __launch_bounds__(256) void gemm_bt(
    const u16* __restrict__ A, const u16* __restrict__ Bt,
    const float* __restrict__ bias,
    int M, int N, int K, int mode,
    u16* __restrict__ qb, u16* __restrict__ kb, u16* __restrict__ vt,
    float* __restrict__ outf) {
  __shared__ u16 As[128][64];   // 16 KB
  __shared__ u16 Bs[128][64];   // 16 KB
  const int tid = threadIdx.x;
  const int lane = tid & 63, wave = tid >> 6;
  const int quad = lane >> 4, l16 = lane & 15;
  const int wy = wave >> 1, wx = wave & 1;  // 2x2 waves, 64x64 each
  const int m0 = blockIdx.x * 128, n0 = blockIdx.y * 128;
  const int srow = lane >> 3, sblk = (lane & 7) ^ (lane >> 3);  // row&7==srow
  const int rsw = l16 & 7;  // read-side swizzle

  f32x4 acc[4][4] = {};

  for (int k0 = 0; k0 < K; k0 += 64) {
#pragma unroll
    for (int i = 0; i < 4; i++) {
      int lr = wave * 32 + i * 8;          // lds row base (mult of 8)
      int row = lr + srow;
      __builtin_amdgcn_global_load_lds(
          (as1cv)(A + (size_t)(m0 + row) * K + k0 + sblk * 8),
          (as3v)(&As[lr][0]), 16, 0, 0);
      __builtin_amdgcn_global_load_lds(
          (as1cv)(Bt + (size_t)(n0 + row) * K + k0 + sblk * 8),
          (as3v)(&Bs[lr][0]), 16, 0, 0);
    }
    __syncthreads();
#pragma unroll
    for (int ks = 0; ks < 2; ks++) {
      const int pcol = ((ks * 4 + quad) ^ rsw) * 8;
      bf16x8 af[4], bfr[4];
#pragma unroll
      for (int i = 0; i < 4; i++)
        af[i] = *(const bf16x8*)&As[wy * 64 + i * 16 + l16][pcol];
#pragma unroll
      for (int j = 0; j < 4; j++)
        bfr[j] = *(const bf16x8*)&Bs[wx * 64 + j * 16 + l16][pcol];
#pragma unroll
      for (int i = 0; i < 4; i++)
#pragma unroll
        for (int j = 0; j < 4; j++)
          acc[i][j] = __builtin_amdgcn_mfma_f32_16x16x32_bf16(af[i], bfr[j], acc[i][j], 0, 0, 0);
    }
    __syncthreads();
  }

  // epilogue: C/D layout col=lane&15, row=quad*4+reg. Branch is block-uniform.
  if (mode == 1) {
#pragma unroll
    for (int i = 0; i < 4; i++)
#pragma unroll
      for (int j = 0; j < 4; j++) {
        int nn = n0 + wx * 64 + j * 16 + l16;
        float bv = bias[nn];
#pragma unroll
        for (int r = 0; r < 4; r++) {
          int mm = m0 + wy * 64 + i * 16 + quad * 4 + r;
          outf[(size_t)mm * N + nn] = acc[i][j][r] + bv;
        }
      }
  } else {
    const int b = m0 >> 11;                       // batch (block-uniform)
    const int tb = (m0 & 2047) + wy * 64 + quad * 4;
    if (n0 < 1024) {        // ---- Q, pre-scaled by 1/sqrt(d)*log2(e) ----
#pragma unroll
      for (int j = 0; j < 4; j++) {
        int nn = n0 + wx * 64 + j * 16 + l16;
        int h = nn >> 6, dd = nn & 63;
        float bv = bias[nn];
        u16* base = qb + ((size_t)(b * HH + h) * TT) * DD + dd;
#pragma unroll
        for (int i = 0; i < 4; i++)
#pragma unroll
          for (int r = 0; r < 4; r++)
            base[(size_t)(tb + i * 16 + r) * DD] =
                f2bf((acc[i][j][r] + bv) * 0.1803368801111f);
      }
    } else if (n0 < 2048) { // ---- K ----
#pragma unroll
      for (int j = 0; j < 4; j++) {
        int nn = n0 + wx * 64 + j * 16 + l16;
        int rem = nn & 1023, h = rem >> 6, dd = rem & 63;
        float bv = bias[nn];
        u16* base = kb + ((size_t)(b * HH + h) * TT) * DD + dd;
#pragma unroll
        for (int i = 0; i < 4; i++)
#pragma unroll
          for (int r = 0; r < 4; r++)
            base[(size_t)(tb + i * 16 + r) * DD] = f2bf(acc[i][j][r] + bv);
      }
    } else {                // ---- V, stored transposed [B,H,D,T] ----
#pragma unroll
      for (int j = 0; j < 4; j++) {
        int nn = n0 + wx * 64 + j * 16 + l16;
        int rem = nn & 1023, h = rem >> 6, dd = rem & 63;
        float bv = bias[nn];
        u16* base = vt + ((size_t)(b * HH + h) * DD + dd) * TT;
#pragma unroll
        for (int i = 0; i < 4; i++)
#pragma unroll
          for (int r = 0; r < 4; r++)
            base[tb + i * 16 + r] = f2bf(acc[i][j][r] + bv);
      }
    }
  }
}

// ---------------- proj GEMM: BM=64 BN=128 (occupancy variant) --------------
// out[8192][1024] = A[8192][1024](bf16) * Bt[1024][1024]^T + bias, fp32 out.
__global__ __launch_bounds__(256) void gemm_proj64(
    const u16* __restrict__ A, const u16* __restrict__ Bt,
    const float* __restrict__ bias, float* __restrict__ outf) {
  constexpr int N = 1024, K = 1024;
  __shared__ u16 As[64][64];    // 8 KB
  __shared__ u16 Bs[128][64];   // 16 KB
  const int tid = threadIdx.x;
  const int lane = tid & 63, wave = tid >> 6;
  const int quad = lane >> 4, l16 = lane & 15;
  const int wy = wave >> 1, wx = wave & 1;  // 2x2 waves, 32x64 each
  const int m0 = blockIdx.x * 64, n0 = blockIdx.y * 128;
  const int srow = lane >> 3, sblk = (lane & 7) ^ (lane >> 3);  // row&7==srow
  const int rsw = l16 & 7;  // read-side swizzle

  f32x4 acc[2][4] = {};

  for (int k0 = 0; k0 < K; k0 += 64) {
#pragma unroll
    for (int i = 0; i < 2; i++) {        // A: 64 rows
      int lr = wave * 16 + i * 8;
      __builtin_amdgcn_global_load_lds(
          (as1cv)(A + (size_t)(m0 + lr + srow) * K + k0 + sblk * 8),
          (as3v)(&As[lr][0]), 16, 0, 0);
    }
#pragma unroll
    for (int i = 0; i < 4; i++) {        // B: 128 rows
      int lr = wave * 32 + i * 8;
      __builtin_amdgcn_global_load_lds(
          (as1cv)(Bt + (size_t)(n0 + lr + srow) * K + k0 + sblk * 8),
          (as3v)(&Bs[lr][0]), 16, 0, 0);
    }
    __syncthreads();
#pragma unroll
    for (int ks = 0; ks < 2; ks++) {
      const int pcol = ((ks * 4 + quad) ^ rsw) * 8;
      bf16x8 af[2], bfr[4];
#pragma unroll
      for (int i = 0; i < 2; i++)
        af[i] = *(const bf16x8*)&As[wy * 32 + i * 16 + l16][pcol];
#pragma unroll
      for (int j = 0; j < 4; j++)
        bfr[j] = *(const bf16x8*)&Bs[wx * 64 + j * 16 + l16][pcol];
#pragma unroll
      for (int i = 0; i < 2; i++)
#pragma unroll
        for (int j = 0; j < 4; j++)
          acc[i][j] = __builtin_amdgcn_mfma_f32_16x16x32_bf16(af[i], bfr[j], acc[i][j], 0, 0, 0);
    }
    __syncthreads();
  }

  // epilogue: C/D layout col=lane&15, row=quad*4+reg
#pragma unroll
  for (int i = 0; i < 2; i++)
#pragma unroll
    for (int j = 0; j < 4; j++) {
      int nn = n0 + wx * 64 + j * 16 + l16;
      float bv = bias[nn];
#pragma unroll
      for (int r = 0; r < 4; r++) {
        int mm = m0 + wy * 32 + i * 16 + quad * 4 + r;
        outf[(size_t)mm * N + nn] = acc[i][j][r] + bv;
      }
    }
}

// ---------------- flash attention (block-cooperative, S^T/O^T) -------------
// grid (bh=64, ty=16); block = 4 waves = 128 q rows. kv rounds of 128.
// Balanced tile perm (R15). Per-f P buffers -> single fence per 64-kv
// block; PV reads V fragments once (shared across f); setprio on MFMA.
__global__ __launch_bounds__(256, 3) void attn_kernel(
    const u16* __restrict__ q_buf, const u16* __restrict__ k_buf,
    const u16* __restrict__ v_t, u16* __restrict__ attn_out) {
  __shared__ __align__(16) u16 Ks[2][64][64];      // K  [kv][d]   16 KB
  __shared__ __align__(16) u16 Vs[2][64][64];      // V^T [d][kv]  16 KB
  __shared__ __align__(16) u16 Pl[4][2][16][64];   // per-wave per-f P 16 KB
  const int tid = threadIdx.x;
  const int lane = tid & 63, wave = tid >> 6;
  const int quad = lane >> 4, l16 = lane & 15;
  const int bh = blockIdx.x;
  const int b = bh >> 4, h = bh & 15;
  // balanced tile permutation: groups of 4 consecutive y sum to 34 units
  const int perm16[16] = {15,14,13,12, 0,1,2,3, 11,10,9,8, 4,5,6,7};
  const int tile = perm16[blockIdx.y];
  const int qt0 = tile * 128;
  const int qw = qt0 + wave * 32;               // wave's first q row
  const u16* Q = q_buf + (size_t)bh * TT * DD;
  const u16* Kp = k_buf + (size_t)bh * TT * DD;
  const u16* Vt = v_t + (size_t)bh * DD * TT;

  // staging geometry: lane -> (row group l>>3, 16B blk (l&7)^(l>>3))
  const int srow = lane >> 3;
  const int sblk = (lane & 7) ^ srow;
  const int swz = l16 & 7;                      // fragment-read swizzle

  bf16x8 qf[2][2];
#pragma unroll
  for (int f = 0; f < 2; f++)
#pragma unroll
    for (int h2 = 0; h2 < 2; h2++)
      qf[f][h2] = *(const bf16x8*)(Q + (size_t)(qw + f * 16 + l16) * DD + h2 * 32 + quad * 8);

  f32x4 o[2][4] = {};   // O^T[d = g*16+quad*4+r][q = l16]
  float l_p[2] = {0.f, 0.f};

  const int my_end = qw + 32;
  const int kv_stop = qt0 + 128;
  for (int kv0 = 0; kv0 < kv_stop; kv0 += 128) {
    // ---- stage both 64-kv halves: K rows and V^T cols ----
#pragma unroll
    for (int hh = 0; hh < 2; hh++)
#pragma unroll
      for (int i = 0; i < 2; i++) {
        int r = wave * 16 + i * 8 + srow;       // lds row 0..63 (row&7==srow)
        __builtin_amdgcn_global_load_lds(
            (as1cv)(Kp + (size_t)(kv0 + hh * 64 + r) * DD + sblk * 8),
            (as3v)(&Ks[hh][wave * 16 + i * 8][0]), 16, 0, 0);
        __builtin_amdgcn_global_load_lds(
            (as1cv)(Vt + (size_t)r * TT + kv0 + hh * 64 + sblk * 8),
            (as3v)(&Vs[hh][wave * 16 + i * 8][0]), 16, 0, 0);
      }
    __syncthreads();

#pragma unroll
    for (int hh = 0; hh < 2; hh++) {
      const int kb0 = kv0 + hh * 64;
      if (kb0 < my_end) {                       // wave-uniform causal skip
        const bool edge = (kb0 + 63 > qw);
        // ---- S^T = K * Q^T ----
        f32x4 s[2][4] = {};
        __builtin_amdgcn_s_setprio(1);
#pragma unroll
        for (int kg = 0; kg < 4; kg++) {
          bf16x8 ka = *(const bf16x8*)&Ks[hh][kg * 16 + l16][(quad ^ swz) * 8];
          bf16x8 kb2 = *(const bf16x8*)&Ks[hh][kg * 16 + l16][((4 + quad) ^ swz) * 8];
#pragma unroll
          for (int f = 0; f < 2; f++) {
            s[f][kg] = __builtin_amdgcn_mfma_f32_16x16x32_bf16(ka, qf[f][0], s[f][kg], 0, 0, 0);
            s[f][kg] = __builtin_amdgcn_mfma_f32_16x16x32_bf16(kb2, qf[f][1], s[f][kg], 0, 0, 0);
          }
        }
        __builtin_amdgcn_s_setprio(0);
        // ---- softmax (fixed-max exp2) + P store, BOTH f ----
#pragma unroll
        for (int f = 0; f < 2; f++) {
          const int qi = qw + f * 16 + l16;
#pragma unroll
          for (int kg = 0; kg < 4; kg++) {
            float v0 = s[f][kg][0], v1 = s[f][kg][1], v2 = s[f][kg][2], v3 = s[f][kg][3];
            if (edge) {
              int kvb = kb0 + kg * 16 + quad * 4;
              v0 = (kvb + 0 <= qi) ? v0 : -1e30f;
              v1 = (kvb + 1 <= qi) ? v1 : -1e30f;
              v2 = (kvb + 2 <= qi) ? v2 : -1e30f;
              v3 = (kvb + 3 <= qi) ? v3 : -1e30f;
            }
            float e0 = __builtin_amdgcn_exp2f(v0);
            float e1 = __builtin_amdgcn_exp2f(v1);
            float e2 = __builtin_amdgcn_exp2f(v2);
            float e3 = __builtin_amdgcn_exp2f(v3);
            l_p[f] += (e0 + e1) + (e2 + e3);
            uint2 pk;
            pk.x = pack2(e0, e1);
            pk.y = pack2(e2, e3);
            // P[q=l16][kv]: 16B blk = kg*2+(quad>>1), swizzled; 8B half = quad&1
            *(uint2*)&Pl[wave][f][l16][((kg * 2 + (quad >> 1)) ^ swz) * 8 + (quad & 1) * 4] = pk;
          }
        }
        __threadfence_block();                  // one DS write->read fence
        // ---- PV: V fragments shared across f, dense MFMA clusters ----
#pragma unroll
        for (int c = 0; c < 2; c++) {
          bf16x8 pa0 = *(const bf16x8*)&Pl[wave][0][l16][((c * 4 + quad) ^ swz) * 8];
          bf16x8 pa1 = *(const bf16x8*)&Pl[wave][1][l16][((c * 4 + quad) ^ swz) * 8];
          __builtin_amdgcn_s_setprio(1);
#pragma unroll
          for (int g = 0; g < 4; g++) {
            bf16x8 vr = *(const bf16x8*)&Vs[hh][g * 16 + l16][((c * 4 + quad) ^ swz) * 8];
            o[0][g] = __builtin_amdgcn_mfma_f32_16x16x32_bf16(vr, pa0, o[0][g], 0, 0, 0);
            o[1][g] = __builtin_amdgcn_mfma_f32_16x16x32_bf16(vr, pa1, o[1][g], 0, 0, 0);
          }
          __builtin_amdgcn_s_setprio(0);
        }
      }
    }
    __syncthreads();
  }

  // epilogue: reduce l across quads, scale, vectorized store
#pragma unroll
  for (int f = 0; f < 2; f++) {
    float l = l_p[f];
    l += __shfl_xor(l, 16);
    l += __shfl_xor(l, 32);
    float inv_l = 1.0f / l;
    int trow = qw + f * 16 + l16;
#pragma unroll
    for (int g = 0; g < 4; g++) {
      ushort4 st;
      st.x = f2bf(o[f][g][0] * inv_l);
      st.y = f2bf(o[f][g][1] * inv_l);
      st.z = f2bf(o[f][g][2] * inv_l);
      st.w = f2bf(o[f][g][3] * inv_l);
      *(ushort4*)(attn_out + ((size_t)(b * TT + trow)) * CC + h * DD + g * 16 + quad * 4) = st;
    }
  }
}

extern "C" void kernel_launch(void* const* d_in, const int* in_sizes, int n_in,
                              void* d_out, int out_size, void* d_ws, size_t ws_size,
                              hipStream_t stream) {
  const float* x = (const float*)d_in[0];
  const float* w_qkv = (const float*)d_in[1];
  const float* b_qkv = (const float*)d_in[2];
  const float* w_proj = (const float*)d_in[3];
  const float* b_proj = (const float*)d_in[4];
  float* out = (float*)d_out;
  char* ws = (char*)d_ws;

  // workspace layout (72 MB total); xb aliases ao (xb dead before attn runs)
  u16* wqkvT = (u16*)(ws);                    // 3072*1024*2 = 6291456
  u16* wprojT = (u16*)(ws + 6291456);         // 1024*1024*2 = 2097152
  u16* qb = (u16*)(ws + 8388608);             // [B,H,T,D] bf16, 16 MB
  u16* kb = (u16*)(ws + 25165824);            // [B,H,T,D] bf16, 16 MB
  u16* vt = (u16*)(ws + 41943040);            // [B,H,D,T] bf16, 16 MB
  u16* ao = (u16*)(ws + 58720256);            // [B,T,C]   bf16, 16 MB
  u16* xb = ao;                               // x cast to bf16 (aliased)

  prep<<<dim3(12288), 256, 0, stream>>>(x, xb, w_qkv, wqkvT, w_proj, wprojT);
  gemm_bt<<<dim3(64, 24), 256, 0, stream>>>(xb, wqkvT, b_qkv, 8192, 3072, 1024, 0,
                                            qb, kb, vt, nullptr);
  attn_kernel<<<dim3(64, 16), 256, 0, stream>>>(qb, kb, vt, ao);
  gemm_proj64<<<dim3(128, 8), 256, 0, stream>>>(ao, wprojT, b_proj, out);
}

// Round 12
// 247.869 us; speedup vs baseline: 1.0002x; 1.0002x over previous
//
#include <hip/hip_runtime.h>
#include <hip/hip_bf16.h>

// MHA: B=4 T=2048 C=1024 H=16 D=64, fp32 in/out, bf16 MFMA internally.
// R20: T1 XCD-aware block swizzle on both GEMMs. QKV stages 768MB of
//      L2/L3 panel reads in 77us (~10 TB/s): round-robin dispatch
//      duplicates every panel into all 8 XCD L2s. Remap 1D grid so each
//      XCD owns a contiguous (M/8 m-tiles x all n-tiles) rectangle:
//      A-panels become L2-resident per XCD, B-panels reused 8x in-XCD.
//      nwg 1536/1024 both %8==0 -> simple bijective swizzle.
//      attn already XCD-local (bh-sharing blocks are 64 apart = same
//      XCD mod 8). Everything else byte-identical to R19/R16.

typedef unsigned short u16;
typedef __bf16 bf16_t;
typedef bf16_t bf16x8 __attribute__((ext_vector_type(8)));
typedef float f32x4 __attribute__((ext_vector_type(4)));
typedef u16 u16x8 __attribute__((ext_vector_type(8)));
typedef const __attribute__((address_space(1))) void* as1cv;
typedef __attribute__((address_space(3))) void* as3v;

#define BB 4
#define TT 2048
#define CC 1024
#define HH 16
#define DD 64

static __device__ __forceinline__ u16 f2bf(float f) {
  union { float f; unsigned int u; } x; x.f = f;
  unsigned int u = x.u;
  u += 0x7fff + ((u >> 16) & 1);   // round-to-nearest-even
  return (u16)(u >> 16);
}

// pack two f32 -> two bf16 (truncation) in one v_perm_b32
static __device__ __forceinline__ unsigned int pack2(float lo, float hi) {
  return __builtin_amdgcn_perm(__float_as_uint(hi), __float_as_uint(lo),
                               0x07060302u);
}

// ---------------- fused prep: x cast + w_qkv^T + w_proj^T ------------------
// blocks [0,8192): cast x (fp32->bf16, 4/thread)
// blocks [8192,11264): transpose+cast w_qkv [1024][3072] -> [3072][1024]
// blocks [11264,12288): transpose+cast w_proj [1024][1024] -> [1024][1024]
__global__ __launch_bounds__(256) void prep(
    const float* __restrict__ x, u16* __restrict__ xb,
    const float* __restrict__ w_qkv, u16* __restrict__ wqkvT,
    const float* __restrict__ w_proj, u16* __restrict__ wprojT) {
  __shared__ float tile[32][33];
  const int id = blockIdx.x;
  if (id < 8192) {
    int i = (id * 256 + threadIdx.x) * 4;
    float4 v = *(const float4*)(x + i);
    ushort4 o;
    o.x = f2bf(v.x); o.y = f2bf(v.y); o.z = f2bf(v.z); o.w = f2bf(v.w);
    *(ushort4*)(xb + i) = o;
    return;
  }
  const float* in; u16* out; int N, n0, k0;
  if (id < 11264) {
    int i = id - 8192;
    in = w_qkv; out = wqkvT; N = 3072;
    n0 = (i % 96) * 32; k0 = (i / 96) * 32;
  } else {
    int i = id - 11264;
    in = w_proj; out = wprojT; N = 1024;
    n0 = (i & 31) * 32; k0 = (i >> 5) * 32;
  }
  const int tx = threadIdx.x & 31, ty = threadIdx.x >> 5;  // 32 x 8
#pragma unroll
  for (int i = 0; i < 32; i += 8)
    tile[ty + i][tx] = in[(size_t)(k0 + ty + i) * N + n0 + tx];
  __syncthreads();
#pragma unroll
  for (int i = 0; i < 32; i += 8)
    out[(size_t)(n0 + ty + i) * 1024 + k0 + tx] = f2bf(tile[tx][ty + i]);
}

// ---------------- GEMM: C[M][N] = A[M][K](bf16) * Bt[N][K]^T + bias --------
// BK=64: per round 8 global_load_lds + 2 sub-steps of (8 ds_read_b128 +
// 16 MFMA). LDS phys 16B slot = logical blk ^ (row & 7).
// 1D grid + T1 XCD chunking: xcd = id&7 owns m-tiles [xcd*mpc, xcd*mpc+mpc)
// across all n-tiles (mpc = M/128/8). Requires (M/128)%8 == 0.
__global__ __launch_bounds__(256) void gemm_bt(
    const u16* __restrict__ A, const u16* __restrict__ Bt,
    const float* __restrict__ bias,
    int M, int N, int K, int mode,
    u16* __restrict__ qb, u16* __restrict__ kb, u16* __restrict__ vt,
    float* __restrict__ outf) {
  __shared__ u16 As[128][64];   // 16 KB
  __shared__ u16 Bs[128][64];   // 16 KB
  const int tid = threadIdx.x;
  const int lane = tid & 63, wave = tid >> 6;
  const int quad = lane >> 4, l16 = lane & 15;
  const int wy = wave >> 1, wx = wave & 1;  // 2x2 waves, 64x64 each
  // T1 XCD-aware chunking (round-robin dispatch: id%8 == XCD)
  const int mpc = (M >> 7) >> 3;            // m-tiles per XCD chunk
  const int id = blockIdx.x;
  const int xcd = id & 7, w = id >> 3;
  const int mi = xcd * mpc + (w % mpc);
  const int ni = w / mpc;
  const int m0 = mi * 128, n0 = ni * 128;
  const int srow = lane >> 3, sblk = (lane & 7) ^ (lane >> 3);  // row&7==srow
  const int rsw = l16 & 7;  // read-side swizzle

  f32x4 acc[4][4] = {};

  for (int k0 = 0; k0 < K; k0 += 64) {
#pragma unroll
    for (int i = 0; i < 4; i++) {
      int lr = wave * 32 + i * 8;          // lds row base (mult of 8)
      int row = lr + srow;
      __builtin_amdgcn_global_load_lds(
          (as1cv)(A + (size_t)(m0 + row) * K + k0 + sblk * 8),
          (as3v)(&As[lr][0]), 16, 0, 0);
      __builtin_amdgcn_global_load_lds(
          (as1cv)(Bt + (size_t)(n0 + row) * K + k0 + sblk * 8),
          (as3v)(&Bs[lr][0]), 16, 0, 0);
    }
    __syncthreads();
#pragma unroll
    for (int ks = 0; ks < 2; ks++) {
      const int pcol = ((ks * 4 + quad) ^ rsw) * 8;
      bf16x8 af[4], bfr[4];
#pragma unroll
      for (int i = 0; i < 4; i++)
        af[i] = *(const bf16x8*)&As[wy * 64 + i * 16 + l16][pcol];
#pragma unroll
      for (int j = 0; j < 4; j++)
        bfr[j] = *(const bf16x8*)&Bs[wx * 64 + j * 16 + l16][pcol];
#pragma unroll
      for (int i = 0; i < 4; i++)
#pragma unroll
        for (int j = 0; j < 4; j++)
          acc[i][j] = __builtin_amdgcn_mfma_f32_16x16x32_bf16(af[i], bfr[j], acc[i][j], 0, 0, 0);
    }
    __syncthreads();
  }

  // epilogue: C/D layout col=lane&15, row=quad*4+reg. Branch is block-uniform.
  if (mode == 1) {
#pragma unroll
    for (int i = 0; i < 4; i++)
#pragma unroll
      for (int j = 0; j < 4; j++) {
        int nn = n0 + wx * 64 + j * 16 + l16;
        float bv = bias[nn];
#pragma unroll
        for (int r = 0; r < 4; r++) {
          int mm = m0 + wy * 64 + i * 16 + quad * 4 + r;
          outf[(size_t)mm * N + nn] = acc[i][j][r] + bv;
        }
      }
  } else {
    const int b = m0 >> 11;                       // batch (block-uniform)
    const int tb = (m0 & 2047) + wy * 64 + quad * 4;
    if (n0 < 1024) {        // ---- Q, pre-scaled by 1/sqrt(d)*log2(e) ----
#pragma unroll
      for (int j = 0; j < 4; j++) {
        int nn = n0 + wx * 64 + j * 16 + l16;
        int h = nn >> 6, dd = nn & 63;
        float bv = bias[nn];
        u16* base = qb + ((size_t)(b * HH + h) * TT) * DD + dd;
#pragma unroll
        for (int i = 0; i < 4; i++)
#pragma unroll
          for (int r = 0; r < 4; r++)
            base[(size_t)(tb + i * 16 + r) * DD] =
                f2bf((acc[i][j][r] + bv) * 0.1803368801111f);
      }
    } else if (n0 < 2048) { // ---- K ----
#pragma unroll
      for (int j = 0; j < 4; j++) {
        int nn = n0 + wx * 64 + j * 16 + l16;
        int rem = nn & 1023, h = rem >> 6, dd = rem & 63;
        float bv = bias[nn];
        u16* base = kb + ((size_t)(b * HH + h) * TT) * DD + dd;
#pragma unroll
        for (int i = 0; i < 4; i++)
#pragma unroll
          for (int r = 0; r < 4; r++)
            base[(size_t)(tb + i * 16 + r) * DD] = f2bf(acc[i][j][r] + bv);
      }
    } else {                // ---- V, stored transposed [B,H,D,T] ----
#pragma unroll
      for (int j = 0; j < 4; j++) {
        int nn = n0 + wx * 64 + j * 16 + l16;
        int rem = nn & 1023, h = rem >> 6, dd = rem & 63;
        float bv = bias[nn];
        u16* base = vt + ((size_t)(b * HH + h) * DD + dd) * TT;
#pragma unroll
        for (int i = 0; i < 4; i++)
#pragma unroll
          for (int r = 0; r < 4; r++)
            base[tb + i * 16 + r] = f2bf(acc[i][j][r] + bv);
      }
    }
  }
}

// ---------------- proj GEMM: BM=64 BN=128 (occupancy variant) --------------
// out[8192][1024] = A[8192][1024](bf16) * Bt[1024][1024]^T + bias, fp32 out.
// 1D grid + T1 XCD chunking: 1024 blocks = 8 chunks of 16 m-tiles x 8 n.
__global__ __launch_bounds__(256) void gemm_proj64(
    const u16* __restrict__ A, const u16* __restrict__ Bt,
    const float* __restrict__ bias, float* __restrict__ outf) {
  constexpr int N = 1024, K = 1024;
  __shared__ u16 As[64][64];    // 8 KB
  __shared__ u16 Bs[128][64];   // 16 KB
  const int tid = threadIdx.x;
  const int lane = tid & 63, wave = tid >> 6;
  const int quad = lane >> 4, l16 = lane & 15;
  const int wy = wave >> 1, wx = wave & 1;  // 2x2 waves, 32x64 each
  const int id = blockIdx.x;
  const int xcd = id & 7, w = id >> 3;      // w in 0..127
  const int m0 = (xcd * 16 + (w & 15)) * 64, n0 = (w >> 4) * 128;
  const int srow = lane >> 3, sblk = (lane & 7) ^ (lane >> 3);  // row&7==srow
  const int rsw = l16 & 7;  // read-side swizzle

  f32x4 acc[2][4] = {};

  for (int k0 = 0; k0 < K; k0 += 64) {
#pragma unroll
    for (int i = 0; i < 2; i++) {        // A: 64 rows
      int lr = wave * 16 + i * 8;
      __builtin_amdgcn_global_load_lds(
          (as1cv)(A + (size_t)(m0 + lr + srow) * K + k0 + sblk * 8),
          (as3v)(&As[lr][0]), 16, 0, 0);
    }
#pragma unroll
    for (int i = 0; i < 4; i++) {        // B: 128 rows
      int lr = wave * 32 + i * 8;
      __builtin_amdgcn_global_load_lds(
          (as1cv)(Bt + (size_t)(n0 + lr + srow) * K + k0 + sblk * 8),
          (as3v)(&Bs[lr][0]), 16, 0, 0);
    }
    __syncthreads();
#pragma unroll
    for (int ks = 0; ks < 2; ks++) {
      const int pcol = ((ks * 4 + quad) ^ rsw) * 8;
      bf16x8 af[2], bfr[4];
#pragma unroll
      for (int i = 0; i < 2; i++)
        af[i] = *(const bf16x8*)&As[wy * 32 + i * 16 + l16][pcol];
#pragma unroll
      for (int j = 0; j < 4; j++)
        bfr[j] = *(const bf16x8*)&Bs[wx * 64 + j * 16 + l16][pcol];
#pragma unroll
      for (int i = 0; i < 2; i++)
#pragma unroll
        for (int j = 0; j < 4; j++)
          acc[i][j] = __builtin_amdgcn_mfma_f32_16x16x32_bf16(af[i], bfr[j], acc[i][j], 0, 0, 0);
    }
    __syncthreads();
  }

  // epilogue: C/D layout col=lane&15, row=quad*4+reg
#pragma unroll
  for (int i = 0; i < 2; i++)
#pragma unroll
    for (int j = 0; j < 4; j++) {
      int nn = n0 + wx * 64 + j * 16 + l16;
      float bv = bias[nn];
#pragma unroll
      for (int r = 0; r < 4; r++) {
        int mm = m0 + wy * 32 + i * 16 + quad * 4 + r;
        outf[(size_t)mm * N + nn] = acc[i][j][r] + bv;
      }
    }
}

// ---------------- flash attention (block-cooperative, S^T/O^T) -------------
// grid (bh=64, ty=16); block = 4 waves = 128 q rows. kv rounds of 128.
// Balanced tile perm (R15). Per-f P buffers -> single fence per 64-kv
// block; PV reads V fragments once (shared across f); setprio on MFMA.
__global__ __launch_bounds__(256, 3) void attn_kernel(
    const u16* __restrict__ q_buf, const u16* __restrict__ k_buf,
    const u16* __restrict__ v_t, u16* __restrict__ attn_out) {
  __shared__ __align__(16) u16 Ks[2][64][64];      // K  [kv][d]   16 KB
  __shared__ __align__(16) u16 Vs[2][64][64];      // V^T [d][kv]  16 KB
  __shared__ __align__(16) u16 Pl[4][2][16][64];   // per-wave per-f P 16 KB
  const int tid = threadIdx.x;
  const int lane = tid & 63, wave = tid >> 6;
  const int quad = lane >> 4, l16 = lane & 15;
  const int bh = blockIdx.x;
  const int b = bh >> 4, h = bh & 15;
  // balanced tile permutation: groups of 4 consecutive y sum to 34 units
  const int perm16[16] = {15,14,13,12, 0,1,2,3, 11,10,9,8, 4,5,6,7};
  const int tile = perm16[blockIdx.y];
  const int qt0 = tile * 128;
  const int qw = qt0 + wave * 32;               // wave's first q row
  const u16* Q = q_buf + (size_t)bh * TT * DD;
  const u16* Kp = k_buf + (size_t)bh * TT * DD;
  const u16* Vt = v_t + (size_t)bh * DD * TT;

  // staging geometry: lane -> (row group l>>3, 16B blk (l&7)^(l>>3))
  const int srow = lane >> 3;
  const int sblk = (lane & 7) ^ srow;
  const int swz = l16 & 7;                      // fragment-read swizzle

  bf16x8 qf[2][2];
#pragma unroll
  for (int f = 0; f < 2; f++)
#pragma unroll
    for (int h2 = 0; h2 < 2; h2++)
      qf[f][h2] = *(const bf16x8*)(Q + (size_t)(qw + f * 16 + l16) * DD + h2 * 32 + quad * 8);

  f32x4 o[2][4] = {};   // O^T[d = g*16+quad*4+r][q = l16]
  float l_p[2] = {0.f, 0.f};

  const int my_end = qw + 32;
  const int kv_stop = qt0 + 128;
  for (int kv0 = 0; kv0 < kv_stop; kv0 += 128) {
    // ---- stage both 64-kv halves: K rows and V^T cols ----
#pragma unroll
    for (int hh = 0; hh < 2; hh++)
#pragma unroll
      for (int i = 0; i < 2; i++) {
        int r = wave * 16 + i * 8 + srow;       // lds row 0..63 (row&7==srow)
        __builtin_amdgcn_global_load_lds(
            (as1cv)(Kp + (size_t)(kv0 + hh * 64 + r) * DD + sblk * 8),
            (as3v)(&Ks[hh][wave * 16 + i * 8][0]), 16, 0, 0);
        __builtin_amdgcn_global_load_lds(
            (as1cv)(Vt + (size_t)r * TT + kv0 + hh * 64 + sblk * 8),
            (as3v)(&Vs[hh][wave * 16 + i * 8][0]), 16, 0, 0);
      }
    __syncthreads();

#pragma unroll
    for (int hh = 0; hh < 2; hh++) {
      const int kb0 = kv0 + hh * 64;
      if (kb0 < my_end) {                       // wave-uniform causal skip
        const bool edge = (kb0 + 63 > qw);
        // ---- S^T = K * Q^T ----
        f32x4 s[2][4] = {};
        __builtin_amdgcn_s_setprio(1);
#pragma unroll
        for (int kg = 0; kg < 4; kg++) {
          bf16x8 ka = *(const bf16x8*)&Ks[hh][kg * 16 + l16][(quad ^ swz) * 8];
          bf16x8 kb2 = *(const bf16x8*)&Ks[hh][kg * 16 + l16][((4 + quad) ^ swz) * 8];
#pragma unroll
          for (int f = 0; f < 2; f++) {
            s[f][kg] = __builtin_amdgcn_mfma_f32_16x16x32_bf16(ka, qf[f][0], s[f][kg], 0, 0, 0);
            s[f][kg] = __builtin_amdgcn_mfma_f32_16x16x32_bf16(kb2, qf[f][1], s[f][kg], 0, 0, 0);
          }
        }
        __builtin_amdgcn_s_setprio(0);
        // ---- softmax (fixed-max exp2) + P store, BOTH f ----
#pragma unroll
        for (int f = 0; f < 2; f++) {
          const int qi = qw + f * 16 + l16;
#pragma unroll
          for (int kg = 0; kg < 4; kg++) {
            float v0 = s[f][kg][0], v1 = s[f][kg][1], v2 = s[f][kg][2], v3 = s[f][kg][3];
            if (edge) {
              int kvb = kb0 + kg * 16 + quad * 4;
              v0 = (kvb + 0 <= qi) ? v0 : -1e30f;
              v1 = (kvb + 1 <= qi) ? v1 : -1e30f;
              v2 = (kvb + 2 <= qi) ? v2 : -1e30f;
              v3 = (kvb + 3 <= qi) ? v3 : -1e30f;
            }
            float e0 = __builtin_amdgcn_exp2f(v0);
            float e1 = __builtin_amdgcn_exp2f(v1);
            float e2 = __builtin_amdgcn_exp2f(v2);
            float e3 = __builtin_amdgcn_exp2f(v3);
            l_p[f] += (e0 + e1) + (e2 + e3);
            uint2 pk;
            pk.x = pack2(e0, e1);
            pk.y = pack2(e2, e3);
            // P[q=l16][kv]: 16B blk = kg*2+(quad>>1), swizzled; 8B half = quad&1
            *(uint2*)&Pl[wave][f][l16][((kg * 2 + (quad >> 1)) ^ swz) * 8 + (quad & 1) * 4] = pk;
          }
        }
        __threadfence_block();                  // one DS write->read fence
        // ---- PV: V fragments shared across f, dense MFMA clusters ----
#pragma unroll
        for (int c = 0; c < 2; c++) {
          bf16x8 pa0 = *(const bf16x8*)&Pl[wave][0][l16][((c * 4 + quad) ^ swz) * 8];
          bf16x8 pa1 = *(const bf16x8*)&Pl[wave][1][l16][((c * 4 + quad) ^ swz) * 8];
          __builtin_amdgcn_s_setprio(1);
#pragma unroll
          for (int g = 0; g < 4; g++) {
            bf16x8 vr = *(const bf16x8*)&Vs[hh][g * 16 + l16][((c * 4 + quad) ^ swz) * 8];
            o[0][g] = __builtin_amdgcn_mfma_f32_16x16x32_bf16(vr, pa0, o[0][g], 0, 0, 0);
            o[1][g] = __builtin_amdgcn_mfma_f32_16x16x32_bf16(vr, pa1, o[1][g], 0, 0, 0);
          }
          __builtin_amdgcn_s_setprio(0);
        }
      }
    }
    __syncthreads();
  }

  // epilogue: reduce l across quads, scale, vectorized store
#pragma unroll
  for (int f = 0; f < 2; f++) {
    float l = l_p[f];
    l += __shfl_xor(l, 16);
    l += __shfl_xor(l, 32);
    float inv_l = 1.0f / l;
    int trow = qw + f * 16 + l16;
#pragma unroll
    for (int g = 0; g < 4; g++) {
      ushort4 st;
      st.x = f2bf(o[f][g][0] * inv_l);
      st.y = f2bf(o[f][g][1] * inv_l);
      st.z = f2bf(o[f][g][2] * inv_l);
      st.w = f2bf(o[f][g][3] * inv_l);
      *(ushort4*)(attn_out + ((size_t)(b * TT + trow)) * CC + h * DD + g * 16 + quad * 4) = st;
    }
  }
}

extern "C" void kernel_launch(void* const* d_in, const int* in_sizes, int n_in,
                              void* d_out, int out_size, void* d_ws, size_t ws_size,
                              hipStream_t stream) {
  const float* x = (const float*)d_in[0];
  const float* w_qkv = (const float*)d_in[1];
  const float* b_qkv = (const float*)d_in[2];
  const float* w_proj = (const float*)d_in[3];
  const float* b_proj = (const float*)d_in[4];
  float* out = (float*)d_out;
  char* ws = (char*)d_ws;

  // workspace layout (72 MB total); xb aliases ao (xb dead before attn runs)
  u16* wqkvT = (u16*)(ws);                    // 3072*1024*2 = 6291456
  u16* wprojT = (u16*)(ws + 6291456);         // 1024*1024*2 = 2097152
  u16* qb = (u16*)(ws + 8388608);             // [B,H,T,D] bf16, 16 MB
  u16* kb = (u16*)(ws + 25165824);            // [B,H,T,D] bf16, 16 MB
  u16* vt = (u16*)(ws + 41943040);            // [B,H,D,T] bf16, 16 MB
  u16* ao = (u16*)(ws + 58720256);            // [B,T,C]   bf16, 16 MB
  u16* xb = ao;                               // x cast to bf16 (aliased)

  prep<<<dim3(12288), 256, 0, stream>>>(x, xb, w_qkv, wqkvT, w_proj, wprojT);
  gemm_bt<<<dim3(1536), 256, 0, stream>>>(xb, wqkvT, b_qkv, 8192, 3072, 1024, 0,
                                          qb, kb, vt, nullptr);
  attn_kernel<<<dim3(64, 16), 256, 0, stream>>>(qb, kb, vt, ao);
  gemm_proj64<<<dim3(1024), 256, 0, stream>>>(ao, wprojT, b_proj, out);
}

// Round 13
// 238.555 us; speedup vs baseline: 1.0392x; 1.0390x over previous
//
#include <hip/hip_runtime.h>
#include <hip/hip_bf16.h>

// MHA: B=4 T=2048 C=1024 H=16 D=64, fp32 in/out, bf16 MFMA internally.
// R21: third (final) 256x256 8-phase QKV attempt. Delta vs R9/R10: phases
//      are now SELF-CONTAINED C-quadrants like m201 (q order (mh,nh) =
//      00->01->11->10; reads/phase = 12/4/8/0) instead of R9's all-B-
//      cached phases (reads 12/2/2/4 with every MFMA tied to phase-0
//      loads -> no per-phase ds_read||MFMA overlap; R9's VALUBusy-12%
//      whole-CU-stall signature). Stage schedule (2 lines/phase):
//      ph0/1: A(t1)->buf1 (buf1-A freed prev ph6); ph2/3: B(t0+2)->buf0
//      (freed after ph1); ph4/5: A(t0+2) (freed after ph2); ph6/7:
//      B(t1+2) (freed after ph5). vmcnt(4) at ph3 (completes t1) and ph7
//      (completes t0+2), oldest-first verified; drain 0 on last iter.
//      Buffers compile-time (t0 even->0). Epilogue/addressing verbatim
//      from R9 (correctness-passed). Failure >= 70us -> revert to R19.

typedef unsigned short u16;
typedef __bf16 bf16_t;
typedef bf16_t bf16x8 __attribute__((ext_vector_type(8)));
typedef float f32x4 __attribute__((ext_vector_type(4)));
typedef u16 u16x8 __attribute__((ext_vector_type(8)));
typedef const __attribute__((address_space(1))) void* as1cv;
typedef __attribute__((address_space(3))) void* as3v;

#define BB 4
#define TT 2048
#define CC 1024
#define HH 16
#define DD 64

static __device__ __forceinline__ u16 f2bf(float f) {
  union { float f; unsigned int u; } x; x.f = f;
  unsigned int u = x.u;
  u += 0x7fff + ((u >> 16) & 1);   // round-to-nearest-even
  return (u16)(u >> 16);
}

// pack two f32 -> two bf16 (truncation) in one v_perm_b32
static __device__ __forceinline__ unsigned int pack2(float lo, float hi) {
  return __builtin_amdgcn_perm(__float_as_uint(hi), __float_as_uint(lo),
                               0x07060302u);
}

// ---------------- fused prep: x cast + w_qkv^T + w_proj^T ------------------
__global__ __launch_bounds__(256) void prep(
    const float* __restrict__ x, u16* __restrict__ xb,
    const float* __restrict__ w_qkv, u16* __restrict__ wqkvT,
    const float* __restrict__ w_proj, u16* __restrict__ wprojT) {
  __shared__ float tile[32][33];
  const int id = blockIdx.x;
  if (id < 8192) {
    int i = (id * 256 + threadIdx.x) * 4;
    float4 v = *(const float4*)(x + i);
    ushort4 o;
    o.x = f2bf(v.x); o.y = f2bf(v.y); o.z = f2bf(v.z); o.w = f2bf(v.w);
    *(ushort4*)(xb + i) = o;
    return;
  }
  const float* in; u16* out; int N, n0, k0;
  if (id < 11264) {
    int i = id - 8192;
    in = w_qkv; out = wqkvT; N = 3072;
    n0 = (i % 96) * 32; k0 = (i / 96) * 32;
  } else {
    int i = id - 11264;
    in = w_proj; out = wprojT; N = 1024;
    n0 = (i & 31) * 32; k0 = (i >> 5) * 32;
  }
  const int tx = threadIdx.x & 31, ty = threadIdx.x >> 5;  // 32 x 8
#pragma unroll
  for (int i = 0; i < 32; i += 8)
    tile[ty + i][tx] = in[(size_t)(k0 + ty + i) * N + n0 + tx];
  __syncthreads();
#pragma unroll
  for (int i = 0; i < 32; i += 8)
    out[(size_t)(n0 + ty + i) * 1024 + k0 + tx] = f2bf(tile[tx][ty + i]);
}

// ---------------- QKV GEMM: 256x256, 8 waves, 8-phase/2-K-tile -------------
__global__ __launch_bounds__(512, 2) void gemm_qkv256(
    const u16* __restrict__ A, const u16* __restrict__ Bt,
    const float* __restrict__ bias,
    u16* __restrict__ qb, u16* __restrict__ kb, u16* __restrict__ vt) {
  constexpr int K = 1024;
  __shared__ u16 As[2][256][64];             // 64 KB
  __shared__ u16 Bs[2][256][64];             // 64 KB
  const int tid = threadIdx.x;
  const int lane = tid & 63, wave = tid >> 6;
  const int quad = lane >> 4, l16 = lane & 15;
  const int wr = wave >> 2, wc = wave & 3;   // 2M x 4N waves, 128x64 out each
  const int rsw = l16 & 7;                   // fragment-read swizzle
  const int srow8 = tid >> 3;                // 0..63: row within 64-row line
  const int sblk = (lane & 7) ^ (lane >> 3); // pre-swizzled source blk

  // XCD chunking: 384 blocks -> 8 chunks of 48 = 8mi x 6ni rects
  const int id = blockIdx.x;
  const int ch = id & 7, w = id >> 3;
  const int mi = (ch & 3) * 8 + w / 6;
  const int ni = (ch >> 2) * 6 + w % 6;
  const int m0 = mi * 256, n0 = ni * 256;

  const u16* Ab = A + (size_t)(m0 + srow8) * K + sblk * 8;
  const u16* Bb = Bt + (size_t)(n0 + srow8) * K + sblk * 8;

#define STA(bufd, line, kt) __builtin_amdgcn_global_load_lds(              \
    (as1cv)(Ab + ((line) * 64) * K + (kt) * 64),                           \
    (as3v)(&As[bufd][(line) * 64 + wave * 8][0]), 16, 0, 0)
#define STB(bufd, line, kt) __builtin_amdgcn_global_load_lds(              \
    (as1cv)(Bb + ((line) * 64) * K + (kt) * 64),                           \
    (as3v)(&Bs[bufd][(line) * 64 + wave * 8][0]), 16, 0, 0)
#define LDA(bufd, mf, ks) (*(const bf16x8*)&As[bufd][wr * 128 + (mf) * 16 + l16] \
                                              [(((ks) * 4 + quad) ^ rsw) * 8])
#define LDB(bufd, nf, ks) (*(const bf16x8*)&Bs[bufd][wc * 64 + (nf) * 16 + l16]  \
                                              [(((ks) * 4 + quad) ^ rsw) * 8])
#define MFMA(af, bf, c) __builtin_amdgcn_mfma_f32_16x16x32_bf16(af, bf, c, 0, 0, 0)

  // prologue: tile0 A+B (8 lines) + tile1 B (4); vmcnt(4) -> tile0 landed
  STA(0, 0, 0); STA(0, 1, 0); STA(0, 2, 0); STA(0, 3, 0);
  STB(0, 0, 0); STB(0, 1, 0); STB(0, 2, 0); STB(0, 3, 0);
  STB(1, 0, 1); STB(1, 1, 1); STB(1, 2, 1); STB(1, 3, 1);
  asm volatile("s_waitcnt vmcnt(4)" ::: "memory");
  __builtin_amdgcn_s_barrier();

  f32x4 acc[8][4] = {};
  bf16x8 a[4][2], b0[2][2], b1[2][2];

#pragma unroll 1
  for (int i = 0; i < 8; ++i) {
    const int t1 = 2 * i + 1, t2 = 2 * i + 2, t3 = 2 * i + 3;
    const bool more = (i < 7);

    // ======== tile t0 = 2i (buf 0) ========
    // ph0: read A-mh0(8) + B-nh0(4); stage t1 A lines 0,1 -> buf1
#pragma unroll
    for (int mf = 0; mf < 4; mf++) { a[mf][0] = LDA(0, mf, 0); a[mf][1] = LDA(0, mf, 1); }
#pragma unroll
    for (int nf = 0; nf < 2; nf++) { b0[nf][0] = LDB(0, nf, 0); b0[nf][1] = LDB(0, nf, 1); }
    STA(1, 0, t1); STA(1, 1, t1);
    __builtin_amdgcn_s_barrier();
    __builtin_amdgcn_s_setprio(1);
#pragma unroll
    for (int mf = 0; mf < 4; mf++)
#pragma unroll
      for (int nf = 0; nf < 2; nf++) {
        acc[mf][nf] = MFMA(a[mf][0], b0[nf][0], acc[mf][nf]);
        acc[mf][nf] = MFMA(a[mf][1], b0[nf][1], acc[mf][nf]);
      }
    __builtin_amdgcn_s_setprio(0);
    __builtin_amdgcn_s_barrier();

    // ph1: read B-nh1(4); stage t1 A lines 2,3
#pragma unroll
    for (int nf = 0; nf < 2; nf++) { b1[nf][0] = LDB(0, 2 + nf, 0); b1[nf][1] = LDB(0, 2 + nf, 1); }
    STA(1, 2, t1); STA(1, 3, t1);
    __builtin_amdgcn_s_barrier();
    __builtin_amdgcn_s_setprio(1);
#pragma unroll
    for (int mf = 0; mf < 4; mf++)
#pragma unroll
      for (int nf = 0; nf < 2; nf++) {
        acc[mf][2 + nf] = MFMA(a[mf][0], b1[nf][0], acc[mf][2 + nf]);
        acc[mf][2 + nf] = MFMA(a[mf][1], b1[nf][1], acc[mf][2 + nf]);
      }
    __builtin_amdgcn_s_setprio(0);
    __builtin_amdgcn_s_barrier();

    // ph2: read A-mh1(8) (reuse a regs); stage t2 B lines 0,1 -> buf0
#pragma unroll
    for (int mf = 0; mf < 4; mf++) { a[mf][0] = LDA(0, 4 + mf, 0); a[mf][1] = LDA(0, 4 + mf, 1); }
    if (more) { STB(0, 0, t2); STB(0, 1, t2); }
    __builtin_amdgcn_s_barrier();
    __builtin_amdgcn_s_setprio(1);
#pragma unroll
    for (int mf = 0; mf < 4; mf++)
#pragma unroll
      for (int nf = 0; nf < 2; nf++) {
        acc[4 + mf][2 + nf] = MFMA(a[mf][0], b1[nf][0], acc[4 + mf][2 + nf]);
        acc[4 + mf][2 + nf] = MFMA(a[mf][1], b1[nf][1], acc[4 + mf][2 + nf]);
      }
    __builtin_amdgcn_s_setprio(0);
    __builtin_amdgcn_s_barrier();

    // ph3: no reads; stage t2 B lines 2,3; MFMA a(mh1) x b0; vmcnt
    if (more) { STB(0, 2, t2); STB(0, 3, t2); }
    __builtin_amdgcn_s_barrier();
    __builtin_amdgcn_s_setprio(1);
#pragma unroll
    for (int mf = 0; mf < 4; mf++)
#pragma unroll
      for (int nf = 0; nf < 2; nf++) {
        acc[4 + mf][nf] = MFMA(a[mf][0], b0[nf][0], acc[4 + mf][nf]);
        acc[4 + mf][nf] = MFMA(a[mf][1], b0[nf][1], acc[4 + mf][nf]);
      }
    __builtin_amdgcn_s_setprio(0);
    if (more) asm volatile("s_waitcnt vmcnt(4)" ::: "memory");
    else      asm volatile("s_waitcnt vmcnt(0)" ::: "memory");
    __builtin_amdgcn_s_barrier();

    // ======== tile t1 = 2i+1 (buf 1) ========
    // ph4: read A-mh0(8) + B-nh0(4); stage t2 A lines 0,1 -> buf0
#pragma unroll
    for (int mf = 0; mf < 4; mf++) { a[mf][0] = LDA(1, mf, 0); a[mf][1] = LDA(1, mf, 1); }
#pragma unroll
    for (int nf = 0; nf < 2; nf++) { b0[nf][0] = LDB(1, nf, 0); b0[nf][1] = LDB(1, nf, 1); }
    if (more) { STA(0, 0, t2); STA(0, 1, t2); }
    __builtin_amdgcn_s_barrier();
    __builtin_amdgcn_s_setprio(1);
#pragma unroll
    for (int mf = 0; mf < 4; mf++)
#pragma unroll
      for (int nf = 0; nf < 2; nf++) {
        acc[mf][nf] = MFMA(a[mf][0], b0[nf][0], acc[mf][nf]);
        acc[mf][nf] = MFMA(a[mf][1], b0[nf][1], acc[mf][nf]);
      }
    __builtin_amdgcn_s_setprio(0);
    __builtin_amdgcn_s_barrier();

    // ph5: read B-nh1(4); stage t2 A lines 2,3
#pragma unroll
    for (int nf = 0; nf < 2; nf++) { b1[nf][0] = LDB(1, 2 + nf, 0); b1[nf][1] = LDB(1, 2 + nf, 1); }
    if (more) { STA(0, 2, t2); STA(0, 3, t2); }
    __builtin_amdgcn_s_barrier();
    __builtin_amdgcn_s_setprio(1);
#pragma unroll
    for (int mf = 0; mf < 4; mf++)
#pragma unroll
      for (int nf = 0; nf < 2; nf++) {
        acc[mf][2 + nf] = MFMA(a[mf][0], b1[nf][0], acc[mf][2 + nf]);
        acc[mf][2 + nf] = MFMA(a[mf][1], b1[nf][1], acc[mf][2 + nf]);
      }
    __builtin_amdgcn_s_setprio(0);
    __builtin_amdgcn_s_barrier();

    // ph6: read A-mh1(8); stage t3 B lines 0,1 -> buf1
#pragma unroll
    for (int mf = 0; mf < 4; mf++) { a[mf][0] = LDA(1, 4 + mf, 0); a[mf][1] = LDA(1, 4 + mf, 1); }
    if (more) { STB(1, 0, t3); STB(1, 1, t3); }
    __builtin_amdgcn_s_barrier();
    __builtin_amdgcn_s_setprio(1);
#pragma unroll
    for (int mf = 0; mf < 4; mf++)
#pragma unroll
      for (int nf = 0; nf < 2; nf++) {
        acc[4 + mf][2 + nf] = MFMA(a[mf][0], b1[nf][0], acc[4 + mf][2 + nf]);
        acc[4 + mf][2 + nf] = MFMA(a[mf][1], b1[nf][1], acc[4 + mf][2 + nf]);
      }
    __builtin_amdgcn_s_setprio(0);
    __builtin_amdgcn_s_barrier();

    // ph7: no reads; stage t3 B lines 2,3; MFMA a(mh1) x b0; vmcnt
    if (more) { STB(1, 2, t3); STB(1, 3, t3); }
    __builtin_amdgcn_s_barrier();
    __builtin_amdgcn_s_setprio(1);
#pragma unroll
    for (int mf = 0; mf < 4; mf++)
#pragma unroll
      for (int nf = 0; nf < 2; nf++) {
        acc[4 + mf][nf] = MFMA(a[mf][0], b0[nf][0], acc[4 + mf][nf]);
        acc[4 + mf][nf] = MFMA(a[mf][1], b0[nf][1], acc[4 + mf][nf]);
      }
    __builtin_amdgcn_s_setprio(0);
    if (more) asm volatile("s_waitcnt vmcnt(4)" ::: "memory");
    __builtin_amdgcn_s_barrier();
  }
#undef STA
#undef STB
#undef LDA
#undef LDB
#undef MFMA

  // epilogue (verbatim from R9, correctness-passed): C/D col=lane&15,
  // row=quad*4+reg. Q/K/V segment block-uniform.
  const int b = m0 >> 11;
  const int tb = (m0 & 2047) + wr * 128 + quad * 4;
  const int seg = n0 >> 10;
  if (seg == 0) {           // ---- Q, pre-scaled by 1/sqrt(d)*log2(e) ----
#pragma unroll
    for (int nf = 0; nf < 4; nf++) {
      int nn = n0 + wc * 64 + nf * 16 + l16;
      int hh = (nn & 1023) >> 6, dd = nn & 63;
      float bv = bias[nn];
      u16* base = qb + ((size_t)(b * HH + hh) * TT) * DD + dd;
#pragma unroll
      for (int mf = 0; mf < 8; mf++)
#pragma unroll
        for (int r = 0; r < 4; r++)
          base[(size_t)(tb + mf * 16 + r) * DD] =
              f2bf((acc[mf][nf][r] + bv) * 0.1803368801111f);
    }
  } else if (seg == 1) {    // ---- K ----
#pragma unroll
    for (int nf = 0; nf < 4; nf++) {
      int nn = n0 + wc * 64 + nf * 16 + l16;
      int hh = (nn & 1023) >> 6, dd = nn & 63;
      float bv = bias[nn];
      u16* base = kb + ((size_t)(b * HH + hh) * TT) * DD + dd;
#pragma unroll
      for (int mf = 0; mf < 8; mf++)
#pragma unroll
        for (int r = 0; r < 4; r++)
          base[(size_t)(tb + mf * 16 + r) * DD] = f2bf(acc[mf][nf][r] + bv);
    }
  } else {                  // ---- V, stored transposed [B,H,D,T] ----
#pragma unroll
    for (int nf = 0; nf < 4; nf++) {
      int nn = n0 + wc * 64 + nf * 16 + l16;
      int hh = (nn & 1023) >> 6, dd = nn & 63;
      float bv = bias[nn];
      u16* base = vt + ((size_t)(b * HH + hh) * DD + dd) * TT + tb;
#pragma unroll
      for (int mf = 0; mf < 8; mf++) {
        ushort4 st;
        st.x = f2bf(acc[mf][nf][0] + bv);
        st.y = f2bf(acc[mf][nf][1] + bv);
        st.z = f2bf(acc[mf][nf][2] + bv);
        st.w = f2bf(acc[mf][nf][3] + bv);
        *(ushort4*)(base + mf * 16) = st;
      }
    }
  }
}

// ---------------- proj GEMM: BM=64 BN=128, XCD-chunked -------------------
__global__ __launch_bounds__(256) void gemm_proj64(
    const u16* __restrict__ A, const u16* __restrict__ Bt,
    const float* __restrict__ bias, float* __restrict__ outf) {
  constexpr int N = 1024, K = 1024;
  __shared__ u16 As[64][64];    // 8 KB
  __shared__ u16 Bs[128][64];   // 16 KB
  const int tid = threadIdx.x;
  const int lane = tid & 63, wave = tid >> 6;
  const int quad = lane >> 4, l16 = lane & 15;
  const int wy = wave >> 1, wx = wave & 1;  // 2x2 waves, 32x64 each
  const int id = blockIdx.x;
  const int xcd = id & 7, w = id >> 3;      // w in 0..127
  const int m0 = (xcd * 16 + (w & 15)) * 64, n0 = (w >> 4) * 128;
  const int srow = lane >> 3, sblk = (lane & 7) ^ (lane >> 3);  // row&7==srow
  const int rsw = l16 & 7;  // read-side swizzle

  f32x4 acc[2][4] = {};

  for (int k0 = 0; k0 < K; k0 += 64) {
#pragma unroll
    for (int i = 0; i < 2; i++) {        // A: 64 rows
      int lr = wave * 16 + i * 8;
      __builtin_amdgcn_global_load_lds(
          (as1cv)(A + (size_t)(m0 + lr + srow) * K + k0 + sblk * 8),
          (as3v)(&As[lr][0]), 16, 0, 0);
    }
#pragma unroll
    for (int i = 0; i < 4; i++) {        // B: 128 rows
      int lr = wave * 32 + i * 8;
      __builtin_amdgcn_global_load_lds(
          (as1cv)(Bt + (size_t)(n0 + lr + srow) * K + k0 + sblk * 8),
          (as3v)(&Bs[lr][0]), 16, 0, 0);
    }
    __syncthreads();
#pragma unroll
    for (int ks = 0; ks < 2; ks++) {
      const int pcol = ((ks * 4 + quad) ^ rsw) * 8;
      bf16x8 af[2], bfr[4];
#pragma unroll
      for (int i = 0; i < 2; i++)
        af[i] = *(const bf16x8*)&As[wy * 32 + i * 16 + l16][pcol];
#pragma unroll
      for (int j = 0; j < 4; j++)
        bfr[j] = *(const bf16x8*)&Bs[wx * 64 + j * 16 + l16][pcol];
#pragma unroll
      for (int i = 0; i < 2; i++)
#pragma unroll
        for (int j = 0; j < 4; j++)
          acc[i][j] = __builtin_amdgcn_mfma_f32_16x16x32_bf16(af[i], bfr[j], acc[i][j], 0, 0, 0);
    }
    __syncthreads();
  }

  // epilogue: C/D layout col=lane&15, row=quad*4+reg
#pragma unroll
  for (int i = 0; i < 2; i++)
#pragma unroll
    for (int j = 0; j < 4; j++) {
      int nn = n0 + wx * 64 + j * 16 + l16;
      float bv = bias[nn];
#pragma unroll
      for (int r = 0; r < 4; r++) {
        int mm = m0 + wy * 32 + i * 16 + quad * 4 + r;
        outf[(size_t)mm * N + nn] = acc[i][j][r] + bv;
      }
    }
}

// ---------------- flash attention (block-cooperative, S^T/O^T) -------------
__global__ __launch_bounds__(256, 3) void attn_kernel(
    const u16* __restrict__ q_buf, const u16* __restrict__ k_buf,
    const u16* __restrict__ v_t, u16* __restrict__ attn_out) {
  __shared__ __align__(16) u16 Ks[2][64][64];      // K  [kv][d]   16 KB
  __shared__ __align__(16) u16 Vs[2][64][64];      // V^T [d][kv]  16 KB
  __shared__ __align__(16) u16 Pl[4][2][16][64];   // per-wave per-f P 16 KB
  const int tid = threadIdx.x;
  const int lane = tid & 63, wave = tid >> 6;
  const int quad = lane >> 4, l16 = lane & 15;
  const int bh = blockIdx.x;
  const int b = bh >> 4, h = bh & 15;
  // balanced tile permutation: groups of 4 consecutive y sum to 34 units
  const int perm16[16] = {15,14,13,12, 0,1,2,3, 11,10,9,8, 4,5,6,7};
  const int tile = perm16[blockIdx.y];
  const int qt0 = tile * 128;
  const int qw = qt0 + wave * 32;               // wave's first q row
  const u16* Q = q_buf + (size_t)bh * TT * DD;
  const u16* Kp = k_buf + (size_t)bh * TT * DD;
  const u16* Vt = v_t + (size_t)bh * DD * TT;

  // staging geometry: lane -> (row group l>>3, 16B blk (l&7)^(l>>3))
  const int srow = lane >> 3;
  const int sblk = (lane & 7) ^ srow;
  const int swz = l16 & 7;                      // fragment-read swizzle

  bf16x8 qf[2][2];
#pragma unroll
  for (int f = 0; f < 2; f++)
#pragma unroll
    for (int h2 = 0; h2 < 2; h2++)
      qf[f][h2] = *(const bf16x8*)(Q + (size_t)(qw + f * 16 + l16) * DD + h2 * 32 + quad * 8);

  f32x4 o[2][4] = {};   // O^T[d = g*16+quad*4+r][q = l16]
  float l_p[2] = {0.f, 0.f};

  const int my_end = qw + 32;
  const int kv_stop = qt0 + 128;
  for (int kv0 = 0; kv0 < kv_stop; kv0 += 128) {
    // ---- stage both 64-kv halves: K rows and V^T cols ----
#pragma unroll
    for (int hh = 0; hh < 2; hh++)
#pragma unroll
      for (int i = 0; i < 2; i++) {
        int r = wave * 16 + i * 8 + srow;       // lds row 0..63 (row&7==srow)
        __builtin_amdgcn_global_load_lds(
            (as1cv)(Kp + (size_t)(kv0 + hh * 64 + r) * DD + sblk * 8),
            (as3v)(&Ks[hh][wave * 16 + i * 8][0]), 16, 0, 0);
        __builtin_amdgcn_global_load_lds(
            (as1cv)(Vt + (size_t)r * TT + kv0 + hh * 64 + sblk * 8),
            (as3v)(&Vs[hh][wave * 16 + i * 8][0]), 16, 0, 0);
      }
    __syncthreads();

#pragma unroll
    for (int hh = 0; hh < 2; hh++) {
      const int kb0 = kv0 + hh * 64;
      if (kb0 < my_end) {                       // wave-uniform causal skip
        const bool edge = (kb0 + 63 > qw);
        // ---- S^T = K * Q^T ----
        f32x4 s[2][4] = {};
        __builtin_amdgcn_s_setprio(1);
#pragma unroll
        for (int kg = 0; kg < 4; kg++) {
          bf16x8 ka = *(const bf16x8*)&Ks[hh][kg * 16 + l16][(quad ^ swz) * 8];
          bf16x8 kb2 = *(const bf16x8*)&Ks[hh][kg * 16 + l16][((4 + quad) ^ swz) * 8];
#pragma unroll
          for (int f = 0; f < 2; f++) {
            s[f][kg] = __builtin_amdgcn_mfma_f32_16x16x32_bf16(ka, qf[f][0], s[f][kg], 0, 0, 0);
            s[f][kg] = __builtin_amdgcn_mfma_f32_16x16x32_bf16(kb2, qf[f][1], s[f][kg], 0, 0, 0);
          }
        }
        __builtin_amdgcn_s_setprio(0);
        // ---- softmax (fixed-max exp2) + P store, BOTH f ----
#pragma unroll
        for (int f = 0; f < 2; f++) {
          const int qi = qw + f * 16 + l16;
#pragma unroll
          for (int kg = 0; kg < 4; kg++) {
            float v0 = s[f][kg][0], v1 = s[f][kg][1], v2 = s[f][kg][2], v3 = s[f][kg][3];
            if (edge) {
              int kvb = kb0 + kg * 16 + quad * 4;
              v0 = (kvb + 0 <= qi) ? v0 : -1e30f;
              v1 = (kvb + 1 <= qi) ? v1 : -1e30f;
              v2 = (kvb + 2 <= qi) ? v2 : -1e30f;
              v3 = (kvb + 3 <= qi) ? v3 : -1e30f;
            }
            float e0 = __builtin_amdgcn_exp2f(v0);
            float e1 = __builtin_amdgcn_exp2f(v1);
            float e2 = __builtin_amdgcn_exp2f(v2);
            float e3 = __builtin_amdgcn_exp2f(v3);
            l_p[f] += (e0 + e1) + (e2 + e3);
            uint2 pk;
            pk.x = pack2(e0, e1);
            pk.y = pack2(e2, e3);
            // P[q=l16][kv]: 16B blk = kg*2+(quad>>1), swizzled; 8B half = quad&1
            *(uint2*)&Pl[wave][f][l16][((kg * 2 + (quad >> 1)) ^ swz) * 8 + (quad & 1) * 4] = pk;
          }
        }
        __threadfence_block();                  // one DS write->read fence
        // ---- PV: V fragments shared across f, dense MFMA clusters ----
#pragma unroll
        for (int c = 0; c < 2; c++) {
          bf16x8 pa0 = *(const bf16x8*)&Pl[wave][0][l16][((c * 4 + quad) ^ swz) * 8];
          bf16x8 pa1 = *(const bf16x8*)&Pl[wave][1][l16][((c * 4 + quad) ^ swz) * 8];
          __builtin_amdgcn_s_setprio(1);
#pragma unroll
          for (int g = 0; g < 4; g++) {
            bf16x8 vr = *(const bf16x8*)&Vs[hh][g * 16 + l16][((c * 4 + quad) ^ swz) * 8];
            o[0][g] = __builtin_amdgcn_mfma_f32_16x16x32_bf16(vr, pa0, o[0][g], 0, 0, 0);
            o[1][g] = __builtin_amdgcn_mfma_f32_16x16x32_bf16(vr, pa1, o[1][g], 0, 0, 0);
          }
          __builtin_amdgcn_s_setprio(0);
        }
      }
    }
    __syncthreads();
  }

  // epilogue: reduce l across quads, scale, vectorized store
#pragma unroll
  for (int f = 0; f < 2; f++) {
    float l = l_p[f];
    l += __shfl_xor(l, 16);
    l += __shfl_xor(l, 32);
    float inv_l = 1.0f / l;
    int trow = qw + f * 16 + l16;
#pragma unroll
    for (int g = 0; g < 4; g++) {
      ushort4 st;
      st.x = f2bf(o[f][g][0] * inv_l);
      st.y = f2bf(o[f][g][1] * inv_l);
      st.z = f2bf(o[f][g][2] * inv_l);
      st.w = f2bf(o[f][g][3] * inv_l);
      *(ushort4*)(attn_out + ((size_t)(b * TT + trow)) * CC + h * DD + g * 16 + quad * 4) = st;
    }
  }
}

extern "C" void kernel_launch(void* const* d_in, const int* in_sizes, int n_in,
                              void* d_out, int out_size, void* d_ws, size_t ws_size,
                              hipStream_t stream) {
  const float* x = (const float*)d_in[0];
  const float* w_qkv = (const float*)d_in[1];
  const float* b_qkv = (const float*)d_in[2];
  const float* w_proj = (const float*)d_in[3];
  const float* b_proj = (const float*)d_in[4];
  float* out = (float*)d_out;
  char* ws = (char*)d_ws;

  // workspace layout (72 MB total); xb aliases ao (xb dead before attn runs)
  u16* wqkvT = (u16*)(ws);                    // 3072*1024*2 = 6291456
  u16* wprojT = (u16*)(ws + 6291456);         // 1024*1024*2 = 2097152
  u16* qb = (u16*)(ws + 8388608);             // [B,H,T,D] bf16, 16 MB
  u16* kb = (u16*)(ws + 25165824);            // [B,H,T,D] bf16, 16 MB
  u16* vt = (u16*)(ws + 41943040);            // [B,H,D,T] bf16, 16 MB
  u16* ao = (u16*)(ws + 58720256);            // [B,T,C]   bf16, 16 MB
  u16* xb = ao;                               // x cast to bf16 (aliased)

  prep<<<dim3(12288), 256, 0, stream>>>(x, xb, w_qkv, wqkvT, w_proj, wprojT);
  gemm_qkv256<<<dim3(384), 512, 0, stream>>>(xb, wqkvT, b_qkv, qb, kb, vt);
  attn_kernel<<<dim3(64, 16), 256, 0, stream>>>(qb, kb, vt, ao);
  gemm_proj64<<<dim3(1024), 256, 0, stream>>>(ao, wprojT, b_proj, out);
}